// Round 17
// baseline (51.443 us; speedup 1.0000x reference)
//
#include <hip/hip_runtime.h>
#include <hip/hip_bf16.h>

// OnlineTripletLoss: B=8192, D=128, fp32 embeddings, int32 labels, scalar out.
// Occupancy x traffic combined: r12's two-tile core (32 rows/wave share each
// B-fragment = 8 B/elem LDS reads, 56 VGPR measured) with LDS cut to 18 KB
// per 4-wave block (SINGLE wave-private 4KB buffer; stage g+1 issued after
// lgkmcnt(0) so the buffer recycles; flight hidden by epilogue + 8 waves/SIMD)
// -> 8 blocks/CU = 32 waves/CU (the r10 lever) AND halved LDS traffic (the
// r12 lever). Zero barriers. 2048 blocks = exactly one residency round.
// Row&15 source-pre-swizzle; sqi-deferred epilogue; packed labels;
// deterministic fixed-point finalize.

#define BB 8192
#define DD 128
#define MARGIN 0.2f
#define EPS 1e-12f

#define GCOLS 16
#define COLS_PER_WAVE 256
#define NGROUPS 16                             // COLS_PER_WAVE / GCOLS

typedef __attribute__((ext_vector_type(8))) short short8;
typedef __attribute__((ext_vector_type(4))) float f32x4;

__device__ inline unsigned short f2bf(float f) {
    __hip_bfloat16 h = __float2bfloat16(f);
    unsigned short u;
    __builtin_memcpy(&u, &h, 2);
    return u;
}

// ---- prep: bf16 copy + packed {sq,label} meta + init reduction state -------
__global__ __launch_bounds__(256) void prep_kernel(
    const float* __restrict__ x, const int* __restrict__ lab,
    unsigned short* __restrict__ xb, float2* __restrict__ meta,
    unsigned* __restrict__ hp2, unsigned* __restrict__ mn2,
    unsigned long long* __restrict__ fsum, unsigned* __restrict__ fdone) {
    int t = blockIdx.x * blockDim.x + threadIdx.x;   // 0 .. 8192*32-1
    int row = t >> 5;                                 // 32 threads per row
    const float4 v = reinterpret_cast<const float4*>(x)[t];

    union { unsigned short u[4]; uint2 w; } p;
    p.u[0] = f2bf(v.x); p.u[1] = f2bf(v.y);
    p.u[2] = f2bf(v.z); p.u[3] = f2bf(v.w);
    reinterpret_cast<uint2*>(xb)[t] = p.w;

    float s = v.x * v.x + v.y * v.y + v.z * v.z + v.w * v.w;
    #pragma unroll
    for (int m = 16; m >= 1; m >>= 1) s += __shfl_xor(s, m, 64);  // within 32-lane row group
    if ((t & 31) == 0) meta[row] = make_float2(s, __int_as_float(lab[row]));

    if (t < BB) { hp2[t] = 0u; mn2[t] = 0x7f800000u; }  // 0, +inf
    if (t == 0) { *fsum = 0ull; *fdone = 0u; }
}

// ---- main ------------------------------------------------------------------
// 2048 blocks x 256 thr = 8192 waves = 32/CU. Block = 4 row-waves x one
// 256-col chunk (smeta shared 2KB). Per wave: 32 rows as two 16x16 A-tiles in
// regs; per 16-col group: 4KB B in a SINGLE wave-private LDS buffer
// (4 gload_lds), vmcnt(0) at group top (issued one group earlier), ds_read
// b128 swizzled, 8 MFMA (one B-fragment feeds both tiles), fused epilogue.
__global__ __launch_bounds__(256) void triplet_main(
    const unsigned short* __restrict__ xb, const float2* __restrict__ meta,
    unsigned* __restrict__ hp2, unsigned* __restrict__ mn2) {
    const int tid  = threadIdx.x;
    const int wave = tid >> 6;
    const int lane = tid & 63;
    const int l15  = lane & 15;
    const int lhi  = lane >> 4;

    const int cc    = blockIdx.x >> 6;               // 0..31 col chunk
    const int rw    = (blockIdx.x & 63) * 4 + wave;  // 0..255 row-wave
    const int rbase = rw * 32;
    const int cbase = cc * COLS_PER_WAVE;

    __shared__ unsigned short sbuf[4][GCOLS * DD];   // 4 waves x 4 KB (private)
    __shared__ float2 smeta[COLS_PER_WAVE];          // 2 KB (shared, dup-staged)

    // A fragments: two 16-row tiles, K=128 in 4 slices (held whole kernel).
    // mfma_f32_16x16x32_bf16 A layout: row = lane&15, k = (lane>>4)*8 + i.
    short8 a0[4], a1[4];
    {
        const unsigned short* ar0 = xb + (size_t)(rbase + l15) * DD + lhi * 8;
        const unsigned short* ar1 = ar0 + 16 * DD;
        #pragma unroll
        for (int s = 0; s < 4; ++s) {
            a0[s] = *reinterpret_cast<const short8*>(ar0 + s * 32);
            a1[s] = *reinterpret_cast<const short8*>(ar1 + s * 32);
        }
    }
    // Slot labels (C/D: col = lane&15, row_local = lhi*4 + k), packed bytes.
    unsigned li0 = 0, li1 = 0;
    #pragma unroll
    for (int k = 0; k < 4; ++k) {
        li0 |= ((unsigned)__float_as_int(meta[rbase + lhi * 4 + k].y) & 255u) << (8 * k);
        li1 |= ((unsigned)__float_as_int(meta[rbase + 16 + lhi * 4 + k].y) & 255u) << (8 * k);
    }
    float hp0[4], mn0[4], hp1[4], mn1[4];
    #pragma unroll
    for (int k = 0; k < 4; ++k) {
        hp0[k] = -__builtin_inff(); mn0[k] = __builtin_inff();
        hp1[k] = -__builtin_inff(); mn1[k] = __builtin_inff();
    }

    // Stage one 16-col group (4KB) into this wave's single buffer. LDS dest
    // linear; global SOURCE pre-swizzled: LDS(col,b) = G(col, b^((col&15)<<4)).
    // Per-lane p-offsets: o = p*1024 + lane*16 -> col = p*4 + (lane>>4),
    // inner = ((lane&15) ^ (col&15)) << 4 (all loop-invariant per lane).
    auto stage = [&](int g) {
        const char* sb_ = (const char*)(xb + (size_t)(cbase + g * GCOLS) * DD);
        char* db = (char*)&sbuf[wave][0];
        #pragma unroll
        for (int p = 0; p < 4; ++p) {
            const int col   = p * 4 + lhi;
            const int inner = ((l15 ^ (col & 15)) << 4);
            __builtin_amdgcn_global_load_lds(
                (const __attribute__((address_space(1))) void*)(sb_ + col * 256 + inner),
                (__attribute__((address_space(3))) void*)(db + p * 1024), 16, 0, 0);
        }
    };

    auto body = [&](int g, bool do_stage) {
        // ds_read B fragment (swizzled: col = l15) + col meta; lgkm-counted.
        const char* bb_ = (const char*)&sbuf[wave][0];
        short8 b[4];
        #pragma unroll
        for (int s = 0; s < 4; ++s)
            b[s] = *reinterpret_cast<const short8*>(
                bb_ + l15 * 256 + ((s * 64 + lhi * 16) ^ (l15 << 4)));
        const float2 cm = smeta[g * GCOLS + l15];
        asm volatile("s_waitcnt lgkmcnt(0)" ::: "memory");
        __builtin_amdgcn_sched_barrier(0);          // b in regs; buffer now free
        if (do_stage) stage(g + 1);
        f32x4 acc0 = {}, acc1 = {};
        #pragma unroll
        for (int s = 0; s < 4; ++s) {
            acc0 = __builtin_amdgcn_mfma_f32_16x16x32_bf16(a0[s], b[s], acc0, 0, 0, 0);
            acc1 = __builtin_amdgcn_mfma_f32_16x16x32_bf16(a1[s], b[s], acc1, 0, 0, 0);
        }
        const float sqj = cm.x;
        const int   labj = __float_as_int(cm.y) & 255;
        #pragma unroll
        for (int k = 0; k < 4; ++k) {
            const float d0 = fmaf(acc0[k], -2.0f, sqj);  // sqj - 2 dot (sqi deferred)
            const float d1 = fmaf(acc1[k], -2.0f, sqj);
            const bool e0 = (int)((li0 >> (8 * k)) & 255u) == labj;
            const bool e1 = (int)((li1 >> (8 * k)) & 255u) == labj;
            // self-pair folds into hp: d2' ~ -sqi -> ~0 after +sqi, never wins.
            hp0[k] = fmaxf(hp0[k], e0 ? d0 : -__builtin_inff());
            mn0[k] = fminf(mn0[k], e0 ? __builtin_inff() : d0);
            hp1[k] = fmaxf(hp1[k], e1 ? d1 : -__builtin_inff());
            mn1[k] = fminf(mn1[k], e1 ? __builtin_inff() : d1);
        }
    };

    // Prologue: smeta (2 dup gload_lds per wave -- identical bytes, benign
    // race), then group 0. At each group top vmcnt(0): the pending stage was
    // issued a full group earlier (flight hidden by epilogue + 8 waves/SIMD).
    {
        const char* msrc = (const char*)(meta + cbase);
        #pragma unroll
        for (int p = 0; p < 2; ++p)
            __builtin_amdgcn_global_load_lds(
                (const __attribute__((address_space(1))) void*)(msrc + p * 1024 + lane * 16),
                (__attribute__((address_space(3))) void*)((char*)smeta + p * 1024), 16, 0, 0);
    }
    stage(0);
    #pragma unroll
    for (int g = 0; g < NGROUPS; ++g) {
        asm volatile("s_waitcnt vmcnt(0)" ::: "memory");
        body(g, g + 1 < NGROUPS);
    }

    // Epilogue: add deferred sqi; clamp hp >= 0 (exact: ref max(d*posmask)>=0);
    // reduce across the 16 col-lanes; one atomic pair per row.
    #pragma unroll
    for (int k = 0; k < 4; ++k) {
        const float sqi0 = meta[rbase + lhi * 4 + k].x;
        const float sqi1 = meta[rbase + 16 + lhi * 4 + k].x;
        hp0[k] = fmaxf(sqi0 + hp0[k], 0.0f);  mn0[k] = sqi0 + mn0[k];
        hp1[k] = fmaxf(sqi1 + hp1[k], 0.0f);  mn1[k] = sqi1 + mn1[k];
    }
    #pragma unroll
    for (int m = 1; m < 16; m <<= 1) {
        #pragma unroll
        for (int k = 0; k < 4; ++k) {
            hp0[k] = fmaxf(hp0[k], __shfl_xor(hp0[k], m, 64));
            mn0[k] = fminf(mn0[k], __shfl_xor(mn0[k], m, 64));
            hp1[k] = fmaxf(hp1[k], __shfl_xor(hp1[k], m, 64));
            mn1[k] = fminf(mn1[k], __shfl_xor(mn1[k], m, 64));
        }
    }
    if (l15 == 0) {   // lanes 0,16,32,48 hold the four lhi row-groups
        #pragma unroll
        for (int k = 0; k < 4; ++k) {
            const int i0 = rbase + lhi * 4 + k;
            const int i1 = i0 + 16;
            atomicMax(&hp2[i0], __float_as_uint(hp0[k]));  // >=0: uint order == float order
            atomicMin(&mn2[i0], __float_as_uint(mn0[k]));  // >=0 or +inf
            atomicMax(&hp2[i1], __float_as_uint(hp1[k]));
            atomicMin(&mn2[i1], __float_as_uint(mn1[k]));
        }
    }
}

// ---- finalize: per-row loss + deterministic fixed-point mean ---------------
// hardest_negative = min_neq d (every row has negatives: 64 labels / 8192).
__device__ inline float d_of(float d2) {
    return (d2 > EPS) ? sqrtf(d2) : 0.0f;
}

__global__ __launch_bounds__(1024) void finalize_kernel(
    const unsigned* __restrict__ hp2, const unsigned* __restrict__ mn2,
    unsigned long long* __restrict__ fsum, unsigned* __restrict__ fdone,
    float* __restrict__ out) {
    const int i = blockIdx.x * 1024 + threadIdx.x;   // 8 blocks x 1024 rows
    const float hpv = d_of(__uint_as_float(hp2[i]));
    const float mnv = d_of(__uint_as_float(mn2[i]));
    float acc = fmaxf(hpv - mnv + MARGIN, 0.0f);

    #pragma unroll
    for (int m = 1; m < 64; m <<= 1) acc += __shfl_xor(acc, m, 64);
    __shared__ float ws[16];
    const int wave = threadIdx.x >> 6;
    if ((threadIdx.x & 63) == 0) ws[wave] = acc;
    __syncthreads();
    if (threadIdx.x == 0) {
        float s = 0.0f;
        #pragma unroll
        for (int w = 0; w < 16; ++w) s += ws[w];
        // deterministic: integer atomic adds are order-independent
        atomicAdd(fsum, (unsigned long long)((double)s * 4294967296.0));
        __threadfence();
        const unsigned old = atomicAdd(fdone, 1u);
        if (old == gridDim.x - 1) {
            const unsigned long long total = atomicAdd(fsum, 0ull);
            out[0] = (float)((double)total / 4294967296.0 / (double)BB);
        }
    }
}

extern "C" void kernel_launch(void* const* d_in, const int* in_sizes, int n_in,
                              void* d_out, int out_size, void* d_ws, size_t ws_size,
                              hipStream_t stream) {
    const float* x = (const float*)d_in[0];
    const int* lab = (const int*)d_in[1];
    float* out = (float*)d_out;

    char* ws = (char*)d_ws;
    unsigned short* xb = (unsigned short*)ws;                          // 2 MB
    float2* meta = (float2*)(ws + (size_t)BB * DD * 2);                // 64 KB
    unsigned* hp2 = (unsigned*)(ws + (size_t)BB * DD * 2 + BB * 8);
    unsigned* mn2 = (unsigned*)(ws + (size_t)BB * DD * 2 + BB * 12);
    unsigned long long* fsum = (unsigned long long*)(ws + (size_t)BB * DD * 2 + BB * 16);
    unsigned* fdone = (unsigned*)(ws + (size_t)BB * DD * 2 + BB * 16 + 8);

    prep_kernel<<<(BB * DD / 4) / 256, 256, 0, stream>>>(x, lab, xb, meta, hp2, mn2, fsum, fdone);
    triplet_main<<<2048, 256, 0, stream>>>(xb, meta, hp2, mn2);
    finalize_kernel<<<BB / 1024, 1024, 0, stream>>>(hp2, mn2, fsum, fdone, out);
}

// Round 18
// 48.579 us; speedup vs baseline: 1.0590x; 1.0590x over previous
//
#include <hip/hip_runtime.h>
#include <hip/hip_bf16.h>

// OnlineTripletLoss: B=8192, D=128, fp32 embeddings, int32 labels, scalar out.
// r12 barrier-free two-tile chassis (56 VGPR measured) at full occupancy:
// single 4KB wave-private B buffer + 2KB smeta = 18KB/block -> 8 blocks/CU;
// 2048 blocks x 4 waves = 8192 waves = 32/CU, one residency round.
// ROLLED group loop (r17's full unroll stretched live ranges to 72 VGPR ->
// occupancy halved; r12's rolled loop stays at 56). Stage(g+1) issued after
// lgkmcnt(0) (buffer recycles); vmcnt(0) at group top; flight hidden by
// 8 waves/SIMD TLP. Bijective XCD swizzle: each XCD owns 4 col chunks.
// Row&15 source-pre-swizzle; sqi-deferred epilogue; packed labels;
// deterministic fixed-point finalize.

#define BB 8192
#define DD 128
#define MARGIN 0.2f
#define EPS 1e-12f

#define GCOLS 16
#define COLS_PER_WAVE 256
#define NGROUPS 16                             // COLS_PER_WAVE / GCOLS

typedef __attribute__((ext_vector_type(8))) short short8;
typedef __attribute__((ext_vector_type(4))) float f32x4;

__device__ inline unsigned short f2bf(float f) {
    __hip_bfloat16 h = __float2bfloat16(f);
    unsigned short u;
    __builtin_memcpy(&u, &h, 2);
    return u;
}

// ---- prep: bf16 copy + packed {sq,label} meta + init reduction state -------
__global__ __launch_bounds__(256) void prep_kernel(
    const float* __restrict__ x, const int* __restrict__ lab,
    unsigned short* __restrict__ xb, float2* __restrict__ meta,
    unsigned* __restrict__ hp2, unsigned* __restrict__ mn2,
    unsigned long long* __restrict__ fsum, unsigned* __restrict__ fdone) {
    int t = blockIdx.x * blockDim.x + threadIdx.x;   // 0 .. 8192*32-1
    int row = t >> 5;                                 // 32 threads per row
    const float4 v = reinterpret_cast<const float4*>(x)[t];

    union { unsigned short u[4]; uint2 w; } p;
    p.u[0] = f2bf(v.x); p.u[1] = f2bf(v.y);
    p.u[2] = f2bf(v.z); p.u[3] = f2bf(v.w);
    reinterpret_cast<uint2*>(xb)[t] = p.w;

    float s = v.x * v.x + v.y * v.y + v.z * v.z + v.w * v.w;
    #pragma unroll
    for (int m = 16; m >= 1; m >>= 1) s += __shfl_xor(s, m, 64);  // within 32-lane row group
    if ((t & 31) == 0) meta[row] = make_float2(s, __int_as_float(lab[row]));

    if (t < BB) { hp2[t] = 0u; mn2[t] = 0x7f800000u; }  // 0, +inf
    if (t == 0) { *fsum = 0ull; *fdone = 0u; }
}

// ---- main ------------------------------------------------------------------
// 2048 blocks x 256 thr = 8192 independent waves (32 rows x 256 cols each),
// zero barriers, 32 waves/CU. Per 16-col group: 4KB B in a single wave-private
// LDS buffer (4 gload_lds), ds_read b128 swizzled, 8 MFMA (one B-fragment
// feeds two 16-row A-tiles), fused select/min/max epilogue.
__global__ __launch_bounds__(256) void triplet_main(
    const unsigned short* __restrict__ xb, const float2* __restrict__ meta,
    unsigned* __restrict__ hp2, unsigned* __restrict__ mn2) {
    const int tid  = threadIdx.x;
    const int wave = tid >> 6;
    const int lane = tid & 63;
    const int l15  = lane & 15;
    const int lhi  = lane >> 4;

    // bijective XCD swizzle (2048 % 8 == 0): XCD x gets logical ids
    // [x*256, x*256+256) = col chunks [4x, 4x+4) -> B slice L2-local.
    const int bid = (int)blockIdx.x;
    const int lid = (bid & 7) * 256 + (bid >> 3);
    const int cc    = lid >> 6;                      // 0..31 col chunk
    const int rw    = (lid & 63) * 4 + wave;         // 0..255 row-wave
    const int rbase = rw * 32;
    const int cbase = cc * COLS_PER_WAVE;

    __shared__ unsigned short sbuf[4][GCOLS * DD];   // 4 waves x 4 KB (private)
    __shared__ float2 smeta[COLS_PER_WAVE];          // 2 KB (shared, dup-staged)

    // A fragments: two 16-row tiles, K=128 in 4 slices (held whole kernel).
    // mfma_f32_16x16x32_bf16 A layout: row = lane&15, k = (lane>>4)*8 + i.
    short8 a0[4], a1[4];
    {
        const unsigned short* ar0 = xb + (size_t)(rbase + l15) * DD + lhi * 8;
        const unsigned short* ar1 = ar0 + 16 * DD;
        #pragma unroll
        for (int s = 0; s < 4; ++s) {
            a0[s] = *reinterpret_cast<const short8*>(ar0 + s * 32);
            a1[s] = *reinterpret_cast<const short8*>(ar1 + s * 32);
        }
    }
    // Slot labels (C/D: col = lane&15, row_local = lhi*4 + k), packed bytes.
    unsigned li0 = 0, li1 = 0;
    #pragma unroll
    for (int k = 0; k < 4; ++k) {
        li0 |= ((unsigned)__float_as_int(meta[rbase + lhi * 4 + k].y) & 255u) << (8 * k);
        li1 |= ((unsigned)__float_as_int(meta[rbase + 16 + lhi * 4 + k].y) & 255u) << (8 * k);
    }
    float hp0[4], mn0[4], hp1[4], mn1[4];
    #pragma unroll
    for (int k = 0; k < 4; ++k) {
        hp0[k] = -__builtin_inff(); mn0[k] = __builtin_inff();
        hp1[k] = -__builtin_inff(); mn1[k] = __builtin_inff();
    }

    // Stage one 16-col group (4KB) into this wave's single buffer. LDS dest
    // linear (base + lane*16); global SOURCE pre-swizzled:
    // LDS(col, b) = G(col, b ^ ((col&15)<<4)).
    auto stage = [&](int g) {
        const char* sb_ = (const char*)(xb + (size_t)(cbase + g * GCOLS) * DD);
        char* db = (char*)&sbuf[wave][0];
        #pragma unroll
        for (int p = 0; p < 4; ++p) {
            const int o     = p * 1024 + lane * 16;
            const int col   = o >> 8;
            const int inner = (o & 255) ^ ((col & 15) << 4);
            __builtin_amdgcn_global_load_lds(
                (const __attribute__((address_space(1))) void*)(sb_ + col * 256 + inner),
                (__attribute__((address_space(3))) void*)(db + p * 1024), 16, 0, 0);
        }
    };

    // Prologue: smeta (2 dup gload_lds per wave -- identical bytes, benign
    // race), then group 0.
    {
        const char* msrc = (const char*)(meta + cbase);
        #pragma unroll
        for (int p = 0; p < 2; ++p)
            __builtin_amdgcn_global_load_lds(
                (const __attribute__((address_space(1))) void*)(msrc + p * 1024 + lane * 16),
                (__attribute__((address_space(3))) void*)((char*)smeta + p * 1024), 16, 0, 0);
    }
    stage(0);

    // ROLLED loop (unrolling this stretched live ranges to 72 VGPR in r17).
    for (int g = 0; g < NGROUPS; ++g) {
        asm volatile("s_waitcnt vmcnt(0)" ::: "memory");   // stage g landed
        const char* bb_ = (const char*)&sbuf[wave][0];
        short8 b[4];
        #pragma unroll
        for (int s = 0; s < 4; ++s)
            b[s] = *reinterpret_cast<const short8*>(
                bb_ + l15 * 256 + ((s * 64 + lhi * 16) ^ (l15 << 4)));
        const float2 cm = smeta[g * GCOLS + l15];
        asm volatile("s_waitcnt lgkmcnt(0)" ::: "memory");
        __builtin_amdgcn_sched_barrier(0);          // b in regs; buffer now free
        if (g + 1 < NGROUPS) stage(g + 1);
        f32x4 acc0 = {}, acc1 = {};
        #pragma unroll
        for (int s = 0; s < 4; ++s) {
            acc0 = __builtin_amdgcn_mfma_f32_16x16x32_bf16(a0[s], b[s], acc0, 0, 0, 0);
            acc1 = __builtin_amdgcn_mfma_f32_16x16x32_bf16(a1[s], b[s], acc1, 0, 0, 0);
        }
        const float sqj = cm.x;
        const int   labj = __float_as_int(cm.y) & 255;
        #pragma unroll
        for (int k = 0; k < 4; ++k) {
            const float d0 = fmaf(acc0[k], -2.0f, sqj);  // sqj - 2 dot (sqi deferred)
            const float d1 = fmaf(acc1[k], -2.0f, sqj);
            const bool e0 = (int)((li0 >> (8 * k)) & 255u) == labj;
            const bool e1 = (int)((li1 >> (8 * k)) & 255u) == labj;
            // self-pair folds into hp: d2' ~ -sqi -> ~0 after +sqi, never wins.
            hp0[k] = fmaxf(hp0[k], e0 ? d0 : -__builtin_inff());
            mn0[k] = fminf(mn0[k], e0 ? __builtin_inff() : d0);
            hp1[k] = fmaxf(hp1[k], e1 ? d1 : -__builtin_inff());
            mn1[k] = fminf(mn1[k], e1 ? __builtin_inff() : d1);
        }
    }

    // Epilogue: add deferred sqi; clamp hp >= 0 (exact: ref max(d*posmask)>=0);
    // reduce across the 16 col-lanes; one atomic pair per row.
    #pragma unroll
    for (int k = 0; k < 4; ++k) {
        const float sqi0 = meta[rbase + lhi * 4 + k].x;
        const float sqi1 = meta[rbase + 16 + lhi * 4 + k].x;
        hp0[k] = fmaxf(sqi0 + hp0[k], 0.0f);  mn0[k] = sqi0 + mn0[k];
        hp1[k] = fmaxf(sqi1 + hp1[k], 0.0f);  mn1[k] = sqi1 + mn1[k];
    }
    #pragma unroll
    for (int m = 1; m < 16; m <<= 1) {
        #pragma unroll
        for (int k = 0; k < 4; ++k) {
            hp0[k] = fmaxf(hp0[k], __shfl_xor(hp0[k], m, 64));
            mn0[k] = fminf(mn0[k], __shfl_xor(mn0[k], m, 64));
            hp1[k] = fmaxf(hp1[k], __shfl_xor(hp1[k], m, 64));
            mn1[k] = fminf(mn1[k], __shfl_xor(mn1[k], m, 64));
        }
    }
    if (l15 == 0) {   // lanes 0,16,32,48 hold the four lhi row-groups
        #pragma unroll
        for (int k = 0; k < 4; ++k) {
            const int i0 = rbase + lhi * 4 + k;
            const int i1 = i0 + 16;
            atomicMax(&hp2[i0], __float_as_uint(hp0[k]));  // >=0: uint order == float order
            atomicMin(&mn2[i0], __float_as_uint(mn0[k]));  // >=0 or +inf
            atomicMax(&hp2[i1], __float_as_uint(hp1[k]));
            atomicMin(&mn2[i1], __float_as_uint(mn1[k]));
        }
    }
}

// ---- finalize: per-row loss + deterministic fixed-point mean ---------------
// hardest_negative = min_neq d (every row has negatives: 64 labels / 8192).
__device__ inline float d_of(float d2) {
    return (d2 > EPS) ? sqrtf(d2) : 0.0f;
}

__global__ __launch_bounds__(1024) void finalize_kernel(
    const unsigned* __restrict__ hp2, const unsigned* __restrict__ mn2,
    unsigned long long* __restrict__ fsum, unsigned* __restrict__ fdone,
    float* __restrict__ out) {
    const int i = blockIdx.x * 1024 + threadIdx.x;   // 8 blocks x 1024 rows
    const float hpv = d_of(__uint_as_float(hp2[i]));
    const float mnv = d_of(__uint_as_float(mn2[i]));
    float acc = fmaxf(hpv - mnv + MARGIN, 0.0f);

    #pragma unroll
    for (int m = 1; m < 64; m <<= 1) acc += __shfl_xor(acc, m, 64);
    __shared__ float ws[16];
    const int wave = threadIdx.x >> 6;
    if ((threadIdx.x & 63) == 0) ws[wave] = acc;
    __syncthreads();
    if (threadIdx.x == 0) {
        float s = 0.0f;
        #pragma unroll
        for (int w = 0; w < 16; ++w) s += ws[w];
        // deterministic: integer atomic adds are order-independent
        atomicAdd(fsum, (unsigned long long)((double)s * 4294967296.0));
        __threadfence();
        const unsigned old = atomicAdd(fdone, 1u);
        if (old == gridDim.x - 1) {
            const unsigned long long total = atomicAdd(fsum, 0ull);
            out[0] = (float)((double)total / 4294967296.0 / (double)BB);
        }
    }
}

extern "C" void kernel_launch(void* const* d_in, const int* in_sizes, int n_in,
                              void* d_out, int out_size, void* d_ws, size_t ws_size,
                              hipStream_t stream) {
    const float* x = (const float*)d_in[0];
    const int* lab = (const int*)d_in[1];
    float* out = (float*)d_out;

    char* ws = (char*)d_ws;
    unsigned short* xb = (unsigned short*)ws;                          // 2 MB
    float2* meta = (float2*)(ws + (size_t)BB * DD * 2);                // 64 KB
    unsigned* hp2 = (unsigned*)(ws + (size_t)BB * DD * 2 + BB * 8);
    unsigned* mn2 = (unsigned*)(ws + (size_t)BB * DD * 2 + BB * 12);
    unsigned long long* fsum = (unsigned long long*)(ws + (size_t)BB * DD * 2 + BB * 16);
    unsigned* fdone = (unsigned*)(ws + (size_t)BB * DD * 2 + BB * 16 + 8);

    prep_kernel<<<(BB * DD / 4) / 256, 256, 0, stream>>>(x, lab, xb, meta, hp2, mn2, fsum, fdone);
    triplet_main<<<2048, 256, 0, stream>>>(xb, meta, hp2, mn2);
    finalize_kernel<<<BB / 1024, 1024, 0, stream>>>(hp2, mn2, fsum, fdone, out);
}

// Round 19
// 44.586 us; speedup vs baseline: 1.1538x; 1.0896x over previous
//
#include <hip/hip_runtime.h>
#include <hip/hip_bf16.h>

// OnlineTripletLoss: B=8192, D=128, fp32 embeddings, int32 labels, scalar out.
// The untried matrix cell: BLOCK-SHARED B staging (r10's L2 lever: 64 MB vs
// 512 MB wave-private) x TWO-TILE compute (r12's LDS lever: 8 B/elem reads).
// = r15's design with ONE change: the pipeline loop is ROLLED (#pragma
// unroll 1). r15's full unroll stretched live ranges past the 64-VGPR
// occupancy step; r18 proved this exact two-tile body compiles to 56 VGPR
// when rolled. LDS 26 KB -> 4 blocks/CU x 8 waves = 32 waves/CU.
// 3-buffer ring, raw s_barrier + counted lgkmcnt(0)/vmcnt(1); row&15
// source-pre-swizzle; sqi-deferred epilogue; packed labels; deterministic
// fixed-point finalize.

#define BB 8192
#define DD 128
#define MARGIN 0.2f
#define EPS 1e-12f

#define COLS_PER_BLOCK 256
#define ROWS_PER_BLOCK 256                     // 8 waves x 32 rows
#define STAGE_COLS 32
#define NSTAGES 8                              // COLS_PER_BLOCK / STAGE_COLS
#define STAGE_SHORTS (STAGE_COLS * DD)         // 4096 shorts = 8 KB

typedef __attribute__((ext_vector_type(8))) short short8;
typedef __attribute__((ext_vector_type(4))) float f32x4;

__device__ inline unsigned short f2bf(float f) {
    __hip_bfloat16 h = __float2bfloat16(f);
    unsigned short u;
    __builtin_memcpy(&u, &h, 2);
    return u;
}

// ---- prep: bf16 copy + packed {sq,label} meta + init reduction state -------
__global__ __launch_bounds__(256) void prep_kernel(
    const float* __restrict__ x, const int* __restrict__ lab,
    unsigned short* __restrict__ xb, float2* __restrict__ meta,
    unsigned* __restrict__ hp2, unsigned* __restrict__ mn2,
    unsigned long long* __restrict__ fsum, unsigned* __restrict__ fdone) {
    int t = blockIdx.x * blockDim.x + threadIdx.x;   // 0 .. 8192*32-1
    int row = t >> 5;                                 // 32 threads per row
    const float4 v = reinterpret_cast<const float4*>(x)[t];

    union { unsigned short u[4]; uint2 w; } p;
    p.u[0] = f2bf(v.x); p.u[1] = f2bf(v.y);
    p.u[2] = f2bf(v.z); p.u[3] = f2bf(v.w);
    reinterpret_cast<uint2*>(xb)[t] = p.w;

    float s = v.x * v.x + v.y * v.y + v.z * v.z + v.w * v.w;
    #pragma unroll
    for (int m = 16; m >= 1; m >>= 1) s += __shfl_xor(s, m, 64);  // within 32-lane row group
    if ((t & 31) == 0) meta[row] = make_float2(s, __int_as_float(lab[row]));

    if (t < BB) { hp2[t] = 0u; mn2[t] = 0x7f800000u; }  // 0, +inf
    if (t == 0) { *fsum = 0ull; *fdone = 0u; }
}

// ---- main ------------------------------------------------------------------
// grid (32, 32), 512 threads = 8 waves x 32 rows = 256 rows x 256-col chunk.
// Per stage (32 cols, 8 KB, BLOCK-shared): 1 gload_lds per thread; 3-buffer
// ring; raw barrier + counted vmcnt(1). Each wave reads B-fragments once and
// feeds TWO 16-row A-tiles (8 MFMA per 16-col group).
__global__ __launch_bounds__(512) void triplet_main(
    const unsigned short* __restrict__ xb, const float2* __restrict__ meta,
    unsigned* __restrict__ hp2, unsigned* __restrict__ mn2) {
    const int tid  = threadIdx.x;
    const int wave = tid >> 6;
    const int lane = tid & 63;
    const int l15  = lane & 15;
    const int lhi  = lane >> 4;
    const int rbase = blockIdx.x * ROWS_PER_BLOCK + wave * 32;
    const int cbase = blockIdx.y * COLS_PER_BLOCK;

    __shared__ unsigned short sb[3][STAGE_SHORTS];   // 3 x 8 KB
    __shared__ float2 smeta[COLS_PER_BLOCK];         // 2 KB

    // A fragments: two 16-row tiles, K=128 in 4 slices (held whole kernel).
    // mfma_f32_16x16x32_bf16 A layout: row = lane&15, k = (lane>>4)*8 + i.
    short8 a0[4], a1[4];
    {
        const unsigned short* ar0 = xb + (size_t)(rbase + l15) * DD + lhi * 8;
        const unsigned short* ar1 = ar0 + 16 * DD;
        #pragma unroll
        for (int s = 0; s < 4; ++s) {
            a0[s] = *reinterpret_cast<const short8*>(ar0 + s * 32);
            a1[s] = *reinterpret_cast<const short8*>(ar1 + s * 32);
        }
    }
    // Slot labels (C/D: col = lane&15, row_local = lhi*4 + k), packed bytes.
    unsigned li0 = 0, li1 = 0;
    #pragma unroll
    for (int k = 0; k < 4; ++k) {
        li0 |= ((unsigned)__float_as_int(meta[rbase + lhi * 4 + k].y) & 255u) << (8 * k);
        li1 |= ((unsigned)__float_as_int(meta[rbase + 16 + lhi * 4 + k].y) & 255u) << (8 * k);
    }
    float hp0[4], mn0[4], hp1[4], mn1[4];
    #pragma unroll
    for (int k = 0; k < 4; ++k) {
        hp0[k] = -__builtin_inff(); mn0[k] = __builtin_inff();
        hp1[k] = -__builtin_inff(); mn1[k] = __builtin_inff();
    }

    // Stage 32 cols (8 KB) into sb[buf]: 1 x 16B gload_lds per thread.
    // LDS dest linear (wave-uniform base + lane*16); global SOURCE
    // pre-swizzled: LDS(col, b) = G(col, b ^ ((col&15)<<4)).
    auto stage = [&](int g, int buf) {
        const char* src_base = (const char*)(xb + (size_t)(cbase + g * STAGE_COLS) * DD);
        const int o   = tid * 16;                       // 0..8191
        const int col = o >> 8;                         // 0..31
        const int byt = (o & 255) ^ ((col & 15) << 4);
        const char* src = src_base + col * 256 + byt;
        char* dst = (char*)&sb[buf][0] + wave * 1024;
        __builtin_amdgcn_global_load_lds(
            (const __attribute__((address_space(1))) void*)src,
            (__attribute__((address_space(3))) void*)dst, 16, 0, 0);
    };

    auto compute_group = [&](int st, int gg, const char* base) {
        const int jl = gg * 16 + l15;                   // col within stage (0..31)
        const int rowoff = jl * 256;
        const int swz = (jl & 15) << 4;
        short8 b[4];
        #pragma unroll
        for (int s = 0; s < 4; ++s)
            b[s] = *reinterpret_cast<const short8*>(
                base + rowoff + ((s * 64 + lhi * 16) ^ swz));
        const float2 mj = smeta[st * STAGE_COLS + jl];
        asm volatile("s_waitcnt lgkmcnt(0)" ::: "memory");
        __builtin_amdgcn_sched_barrier(0);              // rule 18 fence
        f32x4 acc0 = {}, acc1 = {};
        #pragma unroll
        for (int s = 0; s < 4; ++s) {
            acc0 = __builtin_amdgcn_mfma_f32_16x16x32_bf16(a0[s], b[s], acc0, 0, 0, 0);
            acc1 = __builtin_amdgcn_mfma_f32_16x16x32_bf16(a1[s], b[s], acc1, 0, 0, 0);
        }
        const float sqj = mj.x;
        const int   labj = __float_as_int(mj.y) & 255;
        #pragma unroll
        for (int k = 0; k < 4; ++k) {
            const float d0 = fmaf(acc0[k], -2.0f, sqj);  // sqj - 2 dot (sqi deferred)
            const float d1 = fmaf(acc1[k], -2.0f, sqj);
            const bool e0 = (int)((li0 >> (8 * k)) & 255u) == labj;
            const bool e1 = (int)((li1 >> (8 * k)) & 255u) == labj;
            // self-pair folds into hp: d2' ~ -sqi -> ~0 after +sqi, never wins.
            hp0[k] = fmaxf(hp0[k], e0 ? d0 : -__builtin_inff());
            mn0[k] = fminf(mn0[k], e0 ? __builtin_inff() : d0);
            hp1[k] = fmaxf(hp1[k], e1 ? d1 : -__builtin_inff());
            mn1[k] = fminf(mn1[k], e1 ? __builtin_inff() : d1);
        }
    };

    // Prologue: smeta (2 dup gload_lds per wave -- identical bytes, benign
    // race, keeps per-wave vmcnt counts uniform), then stages 0,1.
    {
        const char* msrc = (const char*)(meta + cbase);
        #pragma unroll
        for (int p = 0; p < 2; ++p)
            __builtin_amdgcn_global_load_lds(
                (const __attribute__((address_space(1))) void*)(msrc + p * 1024 + lane * 16),
                (__attribute__((address_space(3))) void*)((char*)smeta + p * 1024), 16, 0, 0);
    }
    stage(0, 0);
    stage(1, 1);

    // ROLLED 3-buffer pipeline (r15's unroll cost +16 VGPR -> occupancy halved;
    // forbid unrolling). At top of iter st, outstanding (per-wave FIFO) =
    // {st, st+1} (+2 smeta at st=0, drained by the same wait). vmcnt(1) ->
    // stage st landed, st+1 in flight across the RAW barrier. lgkmcnt(0) ->
    // this wave's reads of buf (st+2)%3 (iter st-1) done before overwrite.
    #pragma unroll 1
    for (int st = 0; st < NSTAGES; ++st) {
        if (st < NSTAGES - 1)
            asm volatile("s_waitcnt lgkmcnt(0) vmcnt(1)" ::: "memory");
        else
            asm volatile("s_waitcnt lgkmcnt(0) vmcnt(0)" ::: "memory");
        __builtin_amdgcn_s_barrier();
        __builtin_amdgcn_sched_barrier(0);
        if (st + 2 < NSTAGES) stage(st + 2, (st + 2) % 3);
        const char* base = (const char*)&sb[st % 3][0];
        compute_group(st, 0, base);
        __builtin_amdgcn_sched_barrier(0);   // keep live sets (and VGPRs) small
        compute_group(st, 1, base);
    }

    // Epilogue: add deferred sqi; clamp hp >= 0 (exact: ref max(d*posmask)>=0);
    // reduce across the 16 col-lanes; one atomic pair per row.
    #pragma unroll
    for (int k = 0; k < 4; ++k) {
        const float sqi0 = meta[rbase + lhi * 4 + k].x;
        const float sqi1 = meta[rbase + 16 + lhi * 4 + k].x;
        hp0[k] = fmaxf(sqi0 + hp0[k], 0.0f);  mn0[k] = sqi0 + mn0[k];
        hp1[k] = fmaxf(sqi1 + hp1[k], 0.0f);  mn1[k] = sqi1 + mn1[k];
    }
    #pragma unroll
    for (int m = 1; m < 16; m <<= 1) {
        #pragma unroll
        for (int k = 0; k < 4; ++k) {
            hp0[k] = fmaxf(hp0[k], __shfl_xor(hp0[k], m, 64));
            mn0[k] = fminf(mn0[k], __shfl_xor(mn0[k], m, 64));
            hp1[k] = fmaxf(hp1[k], __shfl_xor(hp1[k], m, 64));
            mn1[k] = fminf(mn1[k], __shfl_xor(mn1[k], m, 64));
        }
    }
    if (l15 == 0) {   // lanes 0,16,32,48 hold the four lhi row-groups
        #pragma unroll
        for (int k = 0; k < 4; ++k) {
            const int i0 = rbase + lhi * 4 + k;
            const int i1 = i0 + 16;
            atomicMax(&hp2[i0], __float_as_uint(hp0[k]));  // >=0: uint order == float order
            atomicMin(&mn2[i0], __float_as_uint(mn0[k]));  // >=0 or +inf
            atomicMax(&hp2[i1], __float_as_uint(hp1[k]));
            atomicMin(&mn2[i1], __float_as_uint(mn1[k]));
        }
    }
}

// ---- finalize: per-row loss + deterministic fixed-point mean ---------------
// hardest_negative = min_neq d (every row has negatives: 64 labels / 8192).
__device__ inline float d_of(float d2) {
    return (d2 > EPS) ? sqrtf(d2) : 0.0f;
}

__global__ __launch_bounds__(1024) void finalize_kernel(
    const unsigned* __restrict__ hp2, const unsigned* __restrict__ mn2,
    unsigned long long* __restrict__ fsum, unsigned* __restrict__ fdone,
    float* __restrict__ out) {
    const int i = blockIdx.x * 1024 + threadIdx.x;   // 8 blocks x 1024 rows
    const float hpv = d_of(__uint_as_float(hp2[i]));
    const float mnv = d_of(__uint_as_float(mn2[i]));
    float acc = fmaxf(hpv - mnv + MARGIN, 0.0f);

    #pragma unroll
    for (int m = 1; m < 64; m <<= 1) acc += __shfl_xor(acc, m, 64);
    __shared__ float ws[16];
    const int wave = threadIdx.x >> 6;
    if ((threadIdx.x & 63) == 0) ws[wave] = acc;
    __syncthreads();
    if (threadIdx.x == 0) {
        float s = 0.0f;
        #pragma unroll
        for (int w = 0; w < 16; ++w) s += ws[w];
        // deterministic: integer atomic adds are order-independent
        atomicAdd(fsum, (unsigned long long)((double)s * 4294967296.0));
        __threadfence();
        const unsigned old = atomicAdd(fdone, 1u);
        if (old == gridDim.x - 1) {
            const unsigned long long total = atomicAdd(fsum, 0ull);
            out[0] = (float)((double)total / 4294967296.0 / (double)BB);
        }
    }
}

extern "C" void kernel_launch(void* const* d_in, const int* in_sizes, int n_in,
                              void* d_out, int out_size, void* d_ws, size_t ws_size,
                              hipStream_t stream) {
    const float* x = (const float*)d_in[0];
    const int* lab = (const int*)d_in[1];
    float* out = (float*)d_out;

    char* ws = (char*)d_ws;
    unsigned short* xb = (unsigned short*)ws;                          // 2 MB
    float2* meta = (float2*)(ws + (size_t)BB * DD * 2);                // 64 KB
    unsigned* hp2 = (unsigned*)(ws + (size_t)BB * DD * 2 + BB * 8);
    unsigned* mn2 = (unsigned*)(ws + (size_t)BB * DD * 2 + BB * 12);
    unsigned long long* fsum = (unsigned long long*)(ws + (size_t)BB * DD * 2 + BB * 16);
    unsigned* fdone = (unsigned*)(ws + (size_t)BB * DD * 2 + BB * 16 + 8);

    prep_kernel<<<(BB * DD / 4) / 256, 256, 0, stream>>>(x, lab, xb, meta, hp2, mn2, fsum, fdone);
    dim3 grid(BB / ROWS_PER_BLOCK, BB / COLS_PER_BLOCK);
    triplet_main<<<grid, 512, 0, stream>>>(xb, meta, hp2, mn2);
    finalize_kernel<<<BB / 1024, 1024, 0, stream>>>(hp2, mn2, fsum, fdone, out);
}